// Round 1
// baseline (4389.425 us; speedup 1.0000x reference)
//
#include <hip/hip_runtime.h>
#include <math.h>

#define NNODES 200000
#define NEDGES 3200000
#define NG     256

static __device__ __forceinline__ float relu_(float x) { return x > 0.f ? x : 0.f; }
static __device__ __forceinline__ float sigmoid_(float x) { return 1.f / (1.f + expf(-x)); }

// ---------------- node encoder: n = relu(relu(nodes@Wn1+bn1)@Wn2+bn2) ----------------
__global__ __launch_bounds__(256) void k_node_enc(
    const float* __restrict__ nodes,
    const float* __restrict__ Wn1, const float* __restrict__ bn1,
    const float* __restrict__ Wn2, const float* __restrict__ bn2,
    float* __restrict__ nbuf)
{
    int v = blockIdx.x * 256 + threadIdx.x;
    if (v >= NNODES) return;
    float acc1[32];
#pragma unroll
    for (int j = 0; j < 32; j++) acc1[j] = bn1[j];
    const float4* xp = (const float4*)(nodes + (size_t)v * 128);
#pragma unroll 1
    for (int k4 = 0; k4 < 32; k4++) {
        float4 x = xp[k4];
        const float* w = Wn1 + k4 * 4 * 32;
#pragma unroll
        for (int j = 0; j < 32; j++) acc1[j] = fmaf(x.x, w[j], acc1[j]);
#pragma unroll
        for (int j = 0; j < 32; j++) acc1[j] = fmaf(x.y, w[32 + j], acc1[j]);
#pragma unroll
        for (int j = 0; j < 32; j++) acc1[j] = fmaf(x.z, w[64 + j], acc1[j]);
#pragma unroll
        for (int j = 0; j < 32; j++) acc1[j] = fmaf(x.w, w[96 + j], acc1[j]);
    }
#pragma unroll
    for (int j = 0; j < 32; j++) acc1[j] = relu_(acc1[j]);
    float acc2[16];
#pragma unroll
    for (int j = 0; j < 16; j++) acc2[j] = bn2[j];
#pragma unroll 1
    for (int k = 0; k < 32; k++) {
        const float* w = Wn2 + k * 16;
        float x = acc1[k];
#pragma unroll
        for (int j = 0; j < 16; j++) acc2[j] = fmaf(x, w[j], acc2[j]);
    }
    float4* o4 = (float4*)(nbuf + (size_t)v * 16);
    o4[0] = make_float4(relu_(acc2[0]), relu_(acc2[1]), relu_(acc2[2]), relu_(acc2[3]));
    o4[1] = make_float4(relu_(acc2[4]), relu_(acc2[5]), relu_(acc2[6]), relu_(acc2[7]));
    o4[2] = make_float4(relu_(acc2[8]), relu_(acc2[9]), relu_(acc2[10]), relu_(acc2[11]));
    o4[3] = make_float4(relu_(acc2[12]), relu_(acc2[13]), relu_(acc2[14]), relu_(acc2[15]));
}

// ---------------- edge encoder (+ egraph, rcount, ecount) ----------------
__global__ __launch_bounds__(256) void k_edge_enc(
    const float* __restrict__ edges, const int* __restrict__ senders,
    const int* __restrict__ receivers, const int* __restrict__ node_graph,
    const float* __restrict__ We1, const float* __restrict__ be1,
    const float* __restrict__ We2, const float* __restrict__ be2,
    float* __restrict__ eout, int* __restrict__ egraph,
    float* __restrict__ rcount, float* __restrict__ ecount)
{
    __shared__ float hist[NG];
    for (int i = threadIdx.x; i < NG; i += 256) hist[i] = 0.f;
    __syncthreads();
    for (int idx = blockIdx.x * 256 + threadIdx.x; idx < NEDGES; idx += gridDim.x * 256) {
        float x[16];
        const float4* xp = (const float4*)(edges + (size_t)idx * 16);
#pragma unroll
        for (int q = 0; q < 4; q++) {
            float4 t = xp[q];
            x[q * 4] = t.x; x[q * 4 + 1] = t.y; x[q * 4 + 2] = t.z; x[q * 4 + 3] = t.w;
        }
        float h1[4];
#pragma unroll
        for (int j = 0; j < 4; j++) h1[j] = be1[j];
#pragma unroll
        for (int k = 0; k < 16; k++) {
            const float* w = We1 + k * 4;
#pragma unroll
            for (int j = 0; j < 4; j++) h1[j] = fmaf(x[k], w[j], h1[j]);
        }
#pragma unroll
        for (int j = 0; j < 4; j++) h1[j] = relu_(h1[j]);
        float h2[8];
#pragma unroll
        for (int j = 0; j < 8; j++) h2[j] = be2[j];
#pragma unroll
        for (int k = 0; k < 4; k++) {
            const float* w = We2 + k * 8;
#pragma unroll
            for (int j = 0; j < 8; j++) h2[j] = fmaf(h1[k], w[j], h2[j]);
        }
        float4* op = (float4*)(eout + (size_t)idx * 8);
        op[0] = make_float4(relu_(h2[0]), relu_(h2[1]), relu_(h2[2]), relu_(h2[3]));
        op[1] = make_float4(relu_(h2[4]), relu_(h2[5]), relu_(h2[6]), relu_(h2[7]));
        int s = senders[idx];
        int gid = node_graph[s];
        egraph[idx] = gid;
        atomicAdd(&hist[gid], 1.f);
        atomicAdd(&rcount[receivers[idx]], 1.f);
    }
    __syncthreads();
    for (int i = threadIdx.x; i < NG; i += 256)
        if (hist[i] != 0.f) atomicAdd(&ecount[i], hist[i]);
}

// ---------------- per-graph node sum (encoder) ----------------
__global__ __launch_bounds__(256) void k_node_gsum(
    const float* __restrict__ nbuf, const int* __restrict__ node_graph,
    float* __restrict__ gsum_n, float* __restrict__ ncount)
{
    __shared__ float bins[NG * 16];
    __shared__ float cnt[NG];
    for (int i = threadIdx.x; i < NG * 16; i += 256) bins[i] = 0.f;
    for (int i = threadIdx.x; i < NG; i += 256) cnt[i] = 0.f;
    __syncthreads();
    for (int v = blockIdx.x * 256 + threadIdx.x; v < NNODES; v += gridDim.x * 256) {
        int gid = node_graph[v];
        const float* np = nbuf + (size_t)v * 16;
#pragma unroll
        for (int j = 0; j < 16; j++) atomicAdd(&bins[gid * 16 + j], np[j]);
        atomicAdd(&cnt[gid], 1.f);
    }
    __syncthreads();
    for (int i = threadIdx.x; i < NG * 16; i += 256)
        if (bins[i] != 0.f) atomicAdd(&gsum_n[i], bins[i]);
    for (int i = threadIdx.x; i < NG; i += 256)
        if (cnt[i] != 0.f) atomicAdd(&ncount[i], cnt[i]);
}

// ---------------- g encoder: g = mean_n @ Wg2 + bg2 (no relu); clears gsum_n ----------------
__global__ __launch_bounds__(256) void k_g_enc(
    float* __restrict__ gsum_n, const float* __restrict__ ncount,
    const float* __restrict__ Wg2, const float* __restrict__ bg2,
    float* __restrict__ g)
{
    int gi = threadIdx.x;
    float c = 1.f / fmaxf(ncount[gi], 1.f);
    float nm[16];
#pragma unroll
    for (int k = 0; k < 16; k++) nm[k] = gsum_n[gi * 16 + k] * c;
    float acc[4];
#pragma unroll
    for (int j = 0; j < 4; j++) acc[j] = bg2[j];
#pragma unroll
    for (int k = 0; k < 16; k++) {
        const float* w = Wg2 + k * 4;
#pragma unroll
        for (int j = 0; j < 4; j++) acc[j] = fmaf(nm[k], w[j], acc[j]);
    }
    *(float4*)(g + gi * 4) = make_float4(acc[0], acc[1], acc[2], acc[3]);
#pragma unroll
    for (int k = 0; k < 16; k++) gsum_n[gi * 16 + k] = 0.f;  // clear for hop use
}

// ---------------- hop: edge update + inc scatter + per-graph edge sum ----------------
__global__ __launch_bounds__(256) void k_edge_hop(
    float* __restrict__ e, const float* __restrict__ nbuf, const float* __restrict__ g,
    const int* __restrict__ senders, const int* __restrict__ receivers,
    const int* __restrict__ egraph,
    const float* __restrict__ He_e, const float* __restrict__ He_s,
    const float* __restrict__ He_g, const float* __restrict__ He_b,
    float* __restrict__ inc, float* __restrict__ gsum_e)
{
    __shared__ float bins[NG * 8];
    for (int i = threadIdx.x; i < NG * 8; i += 256) bins[i] = 0.f;
    __syncthreads();
    for (int idx = blockIdx.x * 256 + threadIdx.x; idx < NEDGES; idx += gridDim.x * 256) {
        float ev[8];
        {
            const float4* p = (const float4*)(e + (size_t)idx * 8);
            float4 a = p[0], b = p[1];
            ev[0] = a.x; ev[1] = a.y; ev[2] = a.z; ev[3] = a.w;
            ev[4] = b.x; ev[5] = b.y; ev[6] = b.z; ev[7] = b.w;
        }
        int s = senders[idx];
        float ns[16];
        {
            const float4* p = (const float4*)(nbuf + (size_t)s * 16);
#pragma unroll
            for (int q = 0; q < 4; q++) {
                float4 t = p[q];
                ns[q * 4] = t.x; ns[q * 4 + 1] = t.y; ns[q * 4 + 2] = t.z; ns[q * 4 + 3] = t.w;
            }
        }
        int gid = egraph[idx];
        float gv[4];
        {
            float4 t = *(const float4*)(g + gid * 4);
            gv[0] = t.x; gv[1] = t.y; gv[2] = t.z; gv[3] = t.w;
        }
        float acc[8];
#pragma unroll
        for (int j = 0; j < 8; j++) acc[j] = He_b[j];
#pragma unroll
        for (int k = 0; k < 8; k++) {
            const float* w = He_e + k * 8;
#pragma unroll
            for (int j = 0; j < 8; j++) acc[j] = fmaf(ev[k], w[j], acc[j]);
        }
#pragma unroll
        for (int k = 0; k < 16; k++) {
            const float* w = He_s + k * 8;
#pragma unroll
            for (int j = 0; j < 8; j++) acc[j] = fmaf(ns[k], w[j], acc[j]);
        }
#pragma unroll
        for (int k = 0; k < 4; k++) {
            const float* w = He_g + k * 8;
#pragma unroll
            for (int j = 0; j < 8; j++) acc[j] = fmaf(gv[k], w[j], acc[j]);
        }
#pragma unroll
        for (int j = 0; j < 8; j++) acc[j] = relu_(acc[j]);
        {
            float4* p = (float4*)(e + (size_t)idx * 8);
            p[0] = make_float4(acc[0], acc[1], acc[2], acc[3]);
            p[1] = make_float4(acc[4], acc[5], acc[6], acc[7]);
        }
        int r = receivers[idx];
        float* ip = inc + (size_t)r * 8;
#pragma unroll
        for (int j = 0; j < 8; j++) atomicAdd(&ip[j], acc[j]);
#pragma unroll
        for (int j = 0; j < 8; j++) atomicAdd(&bins[gid * 8 + j], acc[j]);
    }
    __syncthreads();
    for (int i = threadIdx.x; i < NG * 8; i += 256)
        if (bins[i] != 0.f) atomicAdd(&gsum_e[i], bins[i]);
}

// ---------------- hop: node update + per-graph node sum; consumes & zeroes inc ----------------
__global__ __launch_bounds__(256) void k_node_hop(
    float* __restrict__ nbuf, float* __restrict__ inc, const float* __restrict__ rcount,
    const float* __restrict__ g, const int* __restrict__ node_graph,
    const float* __restrict__ Hn_n, const float* __restrict__ Hn_in,
    const float* __restrict__ Hn_g, const float* __restrict__ Hn_b,
    float* __restrict__ gsum_n)
{
    __shared__ float bins[NG * 16];
    for (int i = threadIdx.x; i < NG * 16; i += 256) bins[i] = 0.f;
    __syncthreads();
    for (int v = blockIdx.x * 256 + threadIdx.x; v < NNODES; v += gridDim.x * 256) {
        float nv[16];
        {
            const float4* p = (const float4*)(nbuf + (size_t)v * 16);
#pragma unroll
            for (int q = 0; q < 4; q++) {
                float4 t = p[q];
                nv[q * 4] = t.x; nv[q * 4 + 1] = t.y; nv[q * 4 + 2] = t.z; nv[q * 4 + 3] = t.w;
            }
        }
        float iv[8];
        {
            float4* p = (float4*)(inc + (size_t)v * 8);
            float4 a = p[0], b = p[1];
            iv[0] = a.x; iv[1] = a.y; iv[2] = a.z; iv[3] = a.w;
            iv[4] = b.x; iv[5] = b.y; iv[6] = b.z; iv[7] = b.w;
            float4 z = make_float4(0.f, 0.f, 0.f, 0.f);
            p[0] = z; p[1] = z;  // reset for next hop
        }
        float sc = 1.f / fmaxf(rcount[v], 1.f);
#pragma unroll
        for (int j = 0; j < 8; j++) iv[j] *= sc;
        int gid = node_graph[v];
        float gv[4];
        {
            float4 t = *(const float4*)(g + gid * 4);
            gv[0] = t.x; gv[1] = t.y; gv[2] = t.z; gv[3] = t.w;
        }
        float acc[16];
#pragma unroll
        for (int j = 0; j < 16; j++) acc[j] = Hn_b[j];
#pragma unroll
        for (int k = 0; k < 16; k++) {
            const float* w = Hn_n + k * 16;
#pragma unroll
            for (int j = 0; j < 16; j++) acc[j] = fmaf(nv[k], w[j], acc[j]);
        }
#pragma unroll
        for (int k = 0; k < 8; k++) {
            const float* w = Hn_in + k * 16;
#pragma unroll
            for (int j = 0; j < 16; j++) acc[j] = fmaf(iv[k], w[j], acc[j]);
        }
#pragma unroll
        for (int k = 0; k < 4; k++) {
            const float* w = Hn_g + k * 16;
#pragma unroll
            for (int j = 0; j < 16; j++) acc[j] = fmaf(gv[k], w[j], acc[j]);
        }
#pragma unroll
        for (int j = 0; j < 16; j++) acc[j] = relu_(acc[j]);
        {
            float4* p = (float4*)(nbuf + (size_t)v * 16);
            p[0] = make_float4(acc[0], acc[1], acc[2], acc[3]);
            p[1] = make_float4(acc[4], acc[5], acc[6], acc[7]);
            p[2] = make_float4(acc[8], acc[9], acc[10], acc[11]);
            p[3] = make_float4(acc[12], acc[13], acc[14], acc[15]);
        }
#pragma unroll
        for (int j = 0; j < 16; j++) atomicAdd(&bins[gid * 16 + j], acc[j]);
    }
    __syncthreads();
    for (int i = threadIdx.x; i < NG * 16; i += 256)
        if (bins[i] != 0.f) atomicAdd(&gsum_n[i], bins[i]);
}

// ---------------- hop: global update; clears gsum_e/gsum_n ----------------
__global__ __launch_bounds__(256) void k_g_hop(
    float* __restrict__ g, float* __restrict__ gsum_e, float* __restrict__ gsum_n,
    const float* __restrict__ ecount, const float* __restrict__ ncount,
    const float* __restrict__ Hg_e, const float* __restrict__ Hg_n,
    const float* __restrict__ Hg_g, const float* __restrict__ Hg_b)
{
    int gi = threadIdx.x;
    float ce = 1.f / fmaxf(ecount[gi], 1.f);
    float cn = 1.f / fmaxf(ncount[gi], 1.f);
    float em[8], nm[16], gold[4];
#pragma unroll
    for (int k = 0; k < 8; k++) { em[k] = gsum_e[gi * 8 + k] * ce; gsum_e[gi * 8 + k] = 0.f; }
#pragma unroll
    for (int k = 0; k < 16; k++) { nm[k] = gsum_n[gi * 16 + k] * cn; gsum_n[gi * 16 + k] = 0.f; }
    {
        float4 t = *(const float4*)(g + gi * 4);
        gold[0] = t.x; gold[1] = t.y; gold[2] = t.z; gold[3] = t.w;
    }
    float acc[4];
#pragma unroll
    for (int j = 0; j < 4; j++) acc[j] = Hg_b[j];
#pragma unroll
    for (int k = 0; k < 8; k++) {
        const float* w = Hg_e + k * 4;
#pragma unroll
        for (int j = 0; j < 4; j++) acc[j] = fmaf(em[k], w[j], acc[j]);
    }
#pragma unroll
    for (int k = 0; k < 16; k++) {
        const float* w = Hg_n + k * 4;
#pragma unroll
        for (int j = 0; j < 4; j++) acc[j] = fmaf(nm[k], w[j], acc[j]);
    }
#pragma unroll
    for (int k = 0; k < 4; k++) {
        const float* w = Hg_g + k * 4;
#pragma unroll
        for (int j = 0; j < 4; j++) acc[j] = fmaf(gold[k], w[j], acc[j]);
    }
    *(float4*)(g + gi * 4) = make_float4(relu_(acc[0]), relu_(acc[1]), relu_(acc[2]), relu_(acc[3]));
}

// ---------------- readout ----------------
__global__ __launch_bounds__(256) void k_readout(
    const float* __restrict__ nbuf, const float* __restrict__ g,
    const float* __restrict__ Rn, const float* __restrict__ Rn_b,
    const float* __restrict__ Rg, const float* __restrict__ Rg_b,
    float* __restrict__ out)
{
    int i = blockIdx.x * 256 + threadIdx.x;
    if (i < NNODES) {
        const float* np = nbuf + (size_t)i * 16;
        float acc = Rn_b[0];
#pragma unroll
        for (int k = 0; k < 16; k++) acc = fmaf(np[k], Rn[k], acc);
        out[i] = sigmoid_(acc);
    } else if (i < NNODES + NG) {
        int gi = i - NNODES;
        const float* gp = g + gi * 4;
        float acc = Rg_b[0];
#pragma unroll
        for (int k = 0; k < 4; k++) acc = fmaf(gp[k], Rg[k], acc);
        out[i] = sigmoid_(acc);
    }
}

extern "C" void kernel_launch(void* const* d_in, const int* in_sizes, int n_in,
                              void* d_out, int out_size, void* d_ws, size_t ws_size,
                              hipStream_t stream) {
    const float* nodes      = (const float*)d_in[0];
    const float* edges      = (const float*)d_in[1];
    const int*   senders    = (const int*)d_in[2];
    const int*   receivers  = (const int*)d_in[3];
    const int*   node_graph = (const int*)d_in[4];
    const float* We1 = (const float*)d_in[5];
    const float* be1 = (const float*)d_in[6];
    const float* Wn1 = (const float*)d_in[7];
    const float* bn1 = (const float*)d_in[8];
    const float* We2 = (const float*)d_in[9];
    const float* be2 = (const float*)d_in[10];
    const float* Wn2 = (const float*)d_in[11];
    const float* bn2 = (const float*)d_in[12];
    const float* Wg2 = (const float*)d_in[13];
    const float* bg2 = (const float*)d_in[14];
    const float* He_e = (const float*)d_in[15];
    const float* He_s = (const float*)d_in[16];
    const float* He_g = (const float*)d_in[17];
    const float* He_b = (const float*)d_in[18];
    const float* Hn_n = (const float*)d_in[19];
    const float* Hn_in = (const float*)d_in[20];
    const float* Hn_g = (const float*)d_in[21];
    const float* Hn_b = (const float*)d_in[22];
    const float* Hg_e = (const float*)d_in[23];
    const float* Hg_n = (const float*)d_in[24];
    const float* Hg_g = (const float*)d_in[25];
    const float* Hg_b = (const float*)d_in[26];
    const float* Rn   = (const float*)d_in[27];
    const float* Rn_b = (const float*)d_in[28];
    const float* Rg   = (const float*)d_in[29];
    const float* Rg_b = (const float*)d_in[30];
    float* out = (float*)d_out;

    // workspace layout (floats)
    float* e      = (float*)d_ws;                   // E*8
    int*   egraph = (int*)(e + (size_t)NEDGES * 8); // E
    float* nbuf   = (float*)(egraph + NEDGES);      // N*16
    float* inc    = nbuf + (size_t)NNODES * 16;     // N*8   -- zero region starts here
    float* rcount = inc + (size_t)NNODES * 8;       // N
    float* gsum_n = rcount + NNODES;                // G*16
    float* gsum_e = gsum_n + NG * 16;               // G*8
    float* ecount = gsum_e + NG * 8;                // G
    float* ncount = ecount + NG;                    // G
    float* g      = ncount + NG;                    // G*4
    size_t zero_bytes = ((size_t)NNODES * 8 + NNODES + NG * 16 + NG * 8 + NG + NG + NG * 4) * sizeof(float);
    hipMemsetAsync(inc, 0, zero_bytes, stream);

    k_node_enc<<<(NNODES + 255) / 256, 256, 0, stream>>>(nodes, Wn1, bn1, Wn2, bn2, nbuf);
    k_edge_enc<<<2048, 256, 0, stream>>>(edges, senders, receivers, node_graph,
                                         We1, be1, We2, be2, e, egraph, rcount, ecount);
    k_node_gsum<<<512, 256, 0, stream>>>(nbuf, node_graph, gsum_n, ncount);
    k_g_enc<<<1, 256, 0, stream>>>(gsum_n, ncount, Wg2, bg2, g);

    for (int h = 0; h < 3; h++) {
        k_edge_hop<<<1024, 256, 0, stream>>>(e, nbuf, g, senders, receivers, egraph,
                                             He_e, He_s, He_g, He_b, inc, gsum_e);
        k_node_hop<<<512, 256, 0, stream>>>(nbuf, inc, rcount, g, node_graph,
                                            Hn_n, Hn_in, Hn_g, Hn_b, gsum_n);
        k_g_hop<<<1, 256, 0, stream>>>(g, gsum_e, gsum_n, ecount, ncount,
                                       Hg_e, Hg_n, Hg_g, Hg_b);
    }
    k_readout<<<(NNODES + NG + 255) / 256, 256, 0, stream>>>(nbuf, g, Rn, Rn_b, Rg, Rg_b, out);
}

// Round 2
// 1059.006 us; speedup vs baseline: 4.1449x; 4.1449x over previous
//
#include <hip/hip_runtime.h>
#include <math.h>

#define NNODES 200000
#define NEDGES 3200000
#define NG     256
#define NB1    98      // ceil(200000/2048)
#define NSLAB  512

static __device__ __forceinline__ float relu_(float x) { return x > 0.f ? x : 0.f; }
static __device__ __forceinline__ float sigmoid_(float x) { return 1.f / (1.f + expf(-x)); }

// ---------------- node encoder: n = relu(relu(nodes@Wn1+bn1)@Wn2+bn2) ----------------
__global__ __launch_bounds__(256) void k_node_enc(
    const float* __restrict__ nodes,
    const float* __restrict__ Wn1, const float* __restrict__ bn1,
    const float* __restrict__ Wn2, const float* __restrict__ bn2,
    float* __restrict__ nbuf)
{
    int v = blockIdx.x * 256 + threadIdx.x;
    if (v >= NNODES) return;
    float acc1[32];
#pragma unroll
    for (int j = 0; j < 32; j++) acc1[j] = bn1[j];
    const float4* xp = (const float4*)(nodes + (size_t)v * 128);
#pragma unroll 1
    for (int k4 = 0; k4 < 32; k4++) {
        float4 x = xp[k4];
        const float* w = Wn1 + k4 * 4 * 32;
#pragma unroll
        for (int j = 0; j < 32; j++) acc1[j] = fmaf(x.x, w[j], acc1[j]);
#pragma unroll
        for (int j = 0; j < 32; j++) acc1[j] = fmaf(x.y, w[32 + j], acc1[j]);
#pragma unroll
        for (int j = 0; j < 32; j++) acc1[j] = fmaf(x.z, w[64 + j], acc1[j]);
#pragma unroll
        for (int j = 0; j < 32; j++) acc1[j] = fmaf(x.w, w[96 + j], acc1[j]);
    }
#pragma unroll
    for (int j = 0; j < 32; j++) acc1[j] = relu_(acc1[j]);
    float acc2[16];
#pragma unroll
    for (int j = 0; j < 16; j++) acc2[j] = bn2[j];
#pragma unroll 1
    for (int k = 0; k < 32; k++) {
        const float* w = Wn2 + k * 16;
        float x = acc1[k];
#pragma unroll
        for (int j = 0; j < 16; j++) acc2[j] = fmaf(x, w[j], acc2[j]);
    }
    float4* o4 = (float4*)(nbuf + (size_t)v * 16);
    o4[0] = make_float4(relu_(acc2[0]), relu_(acc2[1]), relu_(acc2[2]), relu_(acc2[3]));
    o4[1] = make_float4(relu_(acc2[4]), relu_(acc2[5]), relu_(acc2[6]), relu_(acc2[7]));
    o4[2] = make_float4(relu_(acc2[8]), relu_(acc2[9]), relu_(acc2[10]), relu_(acc2[11]));
    o4[3] = make_float4(relu_(acc2[12]), relu_(acc2[13]), relu_(acc2[14]), relu_(acc2[15]));
}

// ---------------- degree histogram over receivers ----------------
__global__ __launch_bounds__(256) void k_deg(const int* __restrict__ receivers, int* __restrict__ deg)
{
    for (int i = blockIdx.x * 256 + threadIdx.x; i < NEDGES; i += gridDim.x * 256)
        atomicAdd(&deg[receivers[i]], 1);
}

// ---------------- hierarchical exclusive scan of deg -> off, cursor ----------------
__global__ __launch_bounds__(256) void k_scan1(const int* __restrict__ deg, int* __restrict__ bsum)
{
    __shared__ int ts[256];
    int b = blockIdx.x, t = threadIdx.x;
    int base = b * 2048 + t * 8;
    int s = 0;
#pragma unroll
    for (int u = 0; u < 8; u++) { int idx = base + u; if (idx < NNODES) s += deg[idx]; }
    ts[t] = s; __syncthreads();
    for (int ofs = 128; ofs > 0; ofs >>= 1) {
        if (t < ofs) ts[t] += ts[t + ofs];
        __syncthreads();
    }
    if (t == 0) bsum[b] = ts[0];
}

__global__ void k_scan2(const int* __restrict__ bsum, int* __restrict__ bpre)
{
    if (threadIdx.x == 0) {
        int acc = 0;
        for (int i = 0; i < NB1; i++) { bpre[i] = acc; acc += bsum[i]; }
    }
}

__global__ __launch_bounds__(256) void k_scan3(const int* __restrict__ deg, const int* __restrict__ bpre,
                                               int* __restrict__ off, int* __restrict__ cursor)
{
    __shared__ int ts[256];
    int b = blockIdx.x, t = threadIdx.x;
    int base = b * 2048 + t * 8;
    int loc[8]; int s = 0;
#pragma unroll
    for (int u = 0; u < 8; u++) {
        int idx = base + u;
        int d = (idx < NNODES) ? deg[idx] : 0;
        loc[u] = d; s += d;
    }
    ts[t] = s; __syncthreads();
    for (int ofs = 1; ofs < 256; ofs <<= 1) {
        int v = (t >= ofs) ? ts[t - ofs] : 0;
        __syncthreads();
        ts[t] += v;
        __syncthreads();
    }
    int ex = ((t == 0) ? 0 : ts[t - 1]) + bpre[b];
#pragma unroll
    for (int u = 0; u < 8; u++) {
        int idx = base + u;
        if (idx < NNODES) { off[idx] = ex; cursor[idx] = ex; ex += loc[u]; }
    }
    if (b == 0 && t == 0) off[NNODES] = NEDGES;
}

// ---------------- graph start offsets in (sorted) node array ----------------
__global__ __launch_bounds__(256) void k_goff(const int* __restrict__ ng, int* __restrict__ goff)
{
    int v = blockIdx.x * 256 + threadIdx.x;
    if (v >= NNODES) return;
    int a = ng[v];
    if (v == 0) { for (int g = 0; g <= a; g++) goff[g] = 0; }
    else { int b = ng[v - 1]; for (int g = b + 1; g <= a; g++) goff[g] = v; }
    if (v == NNODES - 1) { for (int g = a + 1; g <= NG; g++) goff[g] = NNODES; }
}

// ---------------- edge encoder + scatter to receiver-sorted layout ----------------
__global__ __launch_bounds__(256) void k_edge_enc_scatter(
    const float* __restrict__ edges, const int* __restrict__ senders,
    const int* __restrict__ receivers, const int* __restrict__ node_graph,
    const float* __restrict__ We1, const float* __restrict__ be1,
    const float* __restrict__ We2, const float* __restrict__ be2,
    int* __restrict__ cursor,
    float* __restrict__ e, int* __restrict__ senders_s, float* __restrict__ ecount)
{
    __shared__ float hist[NG];
    for (int i = threadIdx.x; i < NG; i += 256) hist[i] = 0.f;
    __syncthreads();
    for (int idx = blockIdx.x * 256 + threadIdx.x; idx < NEDGES; idx += gridDim.x * 256) {
        float x[16];
        const float4* xp = (const float4*)(edges + (size_t)idx * 16);
#pragma unroll
        for (int q = 0; q < 4; q++) {
            float4 t = xp[q];
            x[q * 4] = t.x; x[q * 4 + 1] = t.y; x[q * 4 + 2] = t.z; x[q * 4 + 3] = t.w;
        }
        float h1[4];
#pragma unroll
        for (int j = 0; j < 4; j++) h1[j] = be1[j];
#pragma unroll
        for (int k = 0; k < 16; k++) {
            const float* w = We1 + k * 4;
#pragma unroll
            for (int j = 0; j < 4; j++) h1[j] = fmaf(x[k], w[j], h1[j]);
        }
#pragma unroll
        for (int j = 0; j < 4; j++) h1[j] = relu_(h1[j]);
        float h2[8];
#pragma unroll
        for (int j = 0; j < 8; j++) h2[j] = be2[j];
#pragma unroll
        for (int k = 0; k < 4; k++) {
            const float* w = We2 + k * 8;
#pragma unroll
            for (int j = 0; j < 8; j++) h2[j] = fmaf(h1[k], w[j], h2[j]);
        }
        int s = senders[idx];
        int r = receivers[idx];
        int gid = node_graph[s];
        int pos = atomicAdd(&cursor[r], 1);
        float4* op = (float4*)(e + (size_t)pos * 8);
        op[0] = make_float4(relu_(h2[0]), relu_(h2[1]), relu_(h2[2]), relu_(h2[3]));
        op[1] = make_float4(relu_(h2[4]), relu_(h2[5]), relu_(h2[6]), relu_(h2[7]));
        senders_s[pos] = s;
        atomicAdd(&hist[gid], 1.f);
    }
    __syncthreads();
    for (int i = threadIdx.x; i < NG; i += 256)
        if (hist[i] != 0.f) atomicAdd(&ecount[i], hist[i]);
}

// ---------------- per-graph node sum via contiguous ranges (exact, no atomics) ----------------
__global__ __launch_bounds__(256) void k_gsum_nodes(
    const float* __restrict__ nbuf, const int* __restrict__ goff, float* __restrict__ gsum_n)
{
    __shared__ float red[256 * 16];
    int g = blockIdx.x, t = threadIdx.x;
    int s = goff[g], eN = goff[g + 1];
    float acc[16];
#pragma unroll
    for (int j = 0; j < 16; j++) acc[j] = 0.f;
    for (int v = s + t; v < eN; v += 256) {
        const float4* p = (const float4*)(nbuf + (size_t)v * 16);
#pragma unroll
        for (int q = 0; q < 4; q++) {
            float4 x = p[q];
            acc[q * 4] += x.x; acc[q * 4 + 1] += x.y; acc[q * 4 + 2] += x.z; acc[q * 4 + 3] += x.w;
        }
    }
#pragma unroll
    for (int j = 0; j < 16; j++) red[t * 16 + j] = acc[j];
    __syncthreads();
    for (int ofs = 128; ofs > 0; ofs >>= 1) {
        if (t < ofs) {
#pragma unroll
            for (int j = 0; j < 16; j++) red[t * 16 + j] += red[(t + ofs) * 16 + j];
        }
        __syncthreads();
    }
    if (t < 16) gsum_n[g * 16 + t] = red[t];
}

// ---------------- g encoder ----------------
__global__ void k_g_enc(
    const float* __restrict__ gsum_n, const int* __restrict__ goff,
    const float* __restrict__ Wg2, const float* __restrict__ bg2,
    float* __restrict__ g)
{
    int gi = threadIdx.x;
    float c = 1.f / fmaxf((float)(goff[gi + 1] - goff[gi]), 1.f);
    float nm[16];
#pragma unroll
    for (int k = 0; k < 16; k++) nm[k] = gsum_n[gi * 16 + k] * c;
    float acc[4];
#pragma unroll
    for (int j = 0; j < 4; j++) acc[j] = bg2[j];
#pragma unroll
    for (int k = 0; k < 16; k++) {
        const float* w = Wg2 + k * 4;
#pragma unroll
        for (int j = 0; j < 4; j++) acc[j] = fmaf(nm[k], w[j], acc[j]);
    }
    *(float4*)(g + gi * 4) = make_float4(acc[0], acc[1], acc[2], acc[3]);
}

// ---------------- hop: edge update (sequential, receiver-sorted) + LDS graph bins -> slab ----------------
__global__ __launch_bounds__(256) void k_edge_hop(
    float* __restrict__ e, const float* __restrict__ nbuf, const float* __restrict__ g,
    const int* __restrict__ senders_s, const int* __restrict__ node_graph,
    const float* __restrict__ He_e, const float* __restrict__ He_s,
    const float* __restrict__ He_g, const float* __restrict__ He_b,
    float* __restrict__ slab)
{
    __shared__ float bins[NG * 8];
    for (int i = threadIdx.x; i < NG * 8; i += 256) bins[i] = 0.f;
    __syncthreads();
    for (int idx = blockIdx.x * 256 + threadIdx.x; idx < NEDGES; idx += gridDim.x * 256) {
        float ev[8];
        {
            const float4* p = (const float4*)(e + (size_t)idx * 8);
            float4 a = p[0], b = p[1];
            ev[0] = a.x; ev[1] = a.y; ev[2] = a.z; ev[3] = a.w;
            ev[4] = b.x; ev[5] = b.y; ev[6] = b.z; ev[7] = b.w;
        }
        int s = senders_s[idx];
        int gid = node_graph[s];
        float ns[16];
        {
            const float4* p = (const float4*)(nbuf + (size_t)s * 16);
#pragma unroll
            for (int q = 0; q < 4; q++) {
                float4 t = p[q];
                ns[q * 4] = t.x; ns[q * 4 + 1] = t.y; ns[q * 4 + 2] = t.z; ns[q * 4 + 3] = t.w;
            }
        }
        float gv[4];
        {
            float4 t = *(const float4*)(g + gid * 4);
            gv[0] = t.x; gv[1] = t.y; gv[2] = t.z; gv[3] = t.w;
        }
        float acc[8];
#pragma unroll
        for (int j = 0; j < 8; j++) acc[j] = He_b[j];
#pragma unroll
        for (int k = 0; k < 8; k++) {
            const float* w = He_e + k * 8;
#pragma unroll
            for (int j = 0; j < 8; j++) acc[j] = fmaf(ev[k], w[j], acc[j]);
        }
#pragma unroll
        for (int k = 0; k < 16; k++) {
            const float* w = He_s + k * 8;
#pragma unroll
            for (int j = 0; j < 8; j++) acc[j] = fmaf(ns[k], w[j], acc[j]);
        }
#pragma unroll
        for (int k = 0; k < 4; k++) {
            const float* w = He_g + k * 8;
#pragma unroll
            for (int j = 0; j < 8; j++) acc[j] = fmaf(gv[k], w[j], acc[j]);
        }
#pragma unroll
        for (int j = 0; j < 8; j++) acc[j] = relu_(acc[j]);
        {
            float4* p = (float4*)(e + (size_t)idx * 8);
            p[0] = make_float4(acc[0], acc[1], acc[2], acc[3]);
            p[1] = make_float4(acc[4], acc[5], acc[6], acc[7]);
        }
#pragma unroll
        for (int j = 0; j < 8; j++) atomicAdd(&bins[gid * 8 + j], acc[j]);
    }
    __syncthreads();
    float* sp = slab + (size_t)blockIdx.x * (NG * 8);
    for (int i = threadIdx.x; i < NG * 8; i += 256) sp[i] = bins[i];
}

// ---------------- reduce slabs -> gsum_e ----------------
__global__ __launch_bounds__(256) void k_gred_e(const float* __restrict__ slab, float* __restrict__ gsum_e)
{
    int tid = blockIdx.x * 256 + threadIdx.x;  // [0, 2048)
    float s = 0.f;
    for (int b = 0; b < NSLAB; b++) s += slab[(size_t)b * (NG * 8) + tid];
    gsum_e[tid] = s;
}

// ---------------- hop: node update; incoming mean = contiguous segment of sorted e ----------------
__global__ __launch_bounds__(256) void k_node_hop(
    float* __restrict__ nbuf, const float* __restrict__ e, const int* __restrict__ off,
    const float* __restrict__ g, const int* __restrict__ node_graph,
    const float* __restrict__ Hn_n, const float* __restrict__ Hn_in,
    const float* __restrict__ Hn_g, const float* __restrict__ Hn_b)
{
    int v = blockIdx.x * 256 + threadIdx.x;
    if (v >= NNODES) return;
    int o0 = off[v], o1 = off[v + 1];
    float iv[8];
#pragma unroll
    for (int j = 0; j < 8; j++) iv[j] = 0.f;
    for (int j = o0; j < o1; j++) {
        const float4* p = (const float4*)(e + (size_t)j * 8);
        float4 a = p[0], b = p[1];
        iv[0] += a.x; iv[1] += a.y; iv[2] += a.z; iv[3] += a.w;
        iv[4] += b.x; iv[5] += b.y; iv[6] += b.z; iv[7] += b.w;
    }
    float sc = 1.f / fmaxf((float)(o1 - o0), 1.f);
#pragma unroll
    for (int j = 0; j < 8; j++) iv[j] *= sc;
    float nv[16];
    {
        const float4* p = (const float4*)(nbuf + (size_t)v * 16);
#pragma unroll
        for (int q = 0; q < 4; q++) {
            float4 t = p[q];
            nv[q * 4] = t.x; nv[q * 4 + 1] = t.y; nv[q * 4 + 2] = t.z; nv[q * 4 + 3] = t.w;
        }
    }
    int gid = node_graph[v];
    float gv[4];
    {
        float4 t = *(const float4*)(g + gid * 4);
        gv[0] = t.x; gv[1] = t.y; gv[2] = t.z; gv[3] = t.w;
    }
    float acc[16];
#pragma unroll
    for (int j = 0; j < 16; j++) acc[j] = Hn_b[j];
#pragma unroll
    for (int k = 0; k < 16; k++) {
        const float* w = Hn_n + k * 16;
#pragma unroll
        for (int j = 0; j < 16; j++) acc[j] = fmaf(nv[k], w[j], acc[j]);
    }
#pragma unroll
    for (int k = 0; k < 8; k++) {
        const float* w = Hn_in + k * 16;
#pragma unroll
        for (int j = 0; j < 16; j++) acc[j] = fmaf(iv[k], w[j], acc[j]);
    }
#pragma unroll
    for (int k = 0; k < 4; k++) {
        const float* w = Hn_g + k * 16;
#pragma unroll
        for (int j = 0; j < 16; j++) acc[j] = fmaf(gv[k], w[j], acc[j]);
    }
    float4* p = (float4*)(nbuf + (size_t)v * 16);
    p[0] = make_float4(relu_(acc[0]), relu_(acc[1]), relu_(acc[2]), relu_(acc[3]));
    p[1] = make_float4(relu_(acc[4]), relu_(acc[5]), relu_(acc[6]), relu_(acc[7]));
    p[2] = make_float4(relu_(acc[8]), relu_(acc[9]), relu_(acc[10]), relu_(acc[11]));
    p[3] = make_float4(relu_(acc[12]), relu_(acc[13]), relu_(acc[14]), relu_(acc[15]));
}

// ---------------- hop: global update ----------------
__global__ void k_g_hop(
    float* __restrict__ g, const float* __restrict__ gsum_e, const float* __restrict__ gsum_n,
    const float* __restrict__ ecount, const int* __restrict__ goff,
    const float* __restrict__ Hg_e, const float* __restrict__ Hg_n,
    const float* __restrict__ Hg_g, const float* __restrict__ Hg_b)
{
    int gi = threadIdx.x;
    float ce = 1.f / fmaxf(ecount[gi], 1.f);
    float cn = 1.f / fmaxf((float)(goff[gi + 1] - goff[gi]), 1.f);
    float em[8], nm[16], gold[4];
#pragma unroll
    for (int k = 0; k < 8; k++) em[k] = gsum_e[gi * 8 + k] * ce;
#pragma unroll
    for (int k = 0; k < 16; k++) nm[k] = gsum_n[gi * 16 + k] * cn;
    {
        float4 t = *(const float4*)(g + gi * 4);
        gold[0] = t.x; gold[1] = t.y; gold[2] = t.z; gold[3] = t.w;
    }
    float acc[4];
#pragma unroll
    for (int j = 0; j < 4; j++) acc[j] = Hg_b[j];
#pragma unroll
    for (int k = 0; k < 8; k++) {
        const float* w = Hg_e + k * 4;
#pragma unroll
        for (int j = 0; j < 4; j++) acc[j] = fmaf(em[k], w[j], acc[j]);
    }
#pragma unroll
    for (int k = 0; k < 16; k++) {
        const float* w = Hg_n + k * 4;
#pragma unroll
        for (int j = 0; j < 4; j++) acc[j] = fmaf(nm[k], w[j], acc[j]);
    }
#pragma unroll
    for (int k = 0; k < 4; k++) {
        const float* w = Hg_g + k * 4;
#pragma unroll
        for (int j = 0; j < 4; j++) acc[j] = fmaf(gold[k], w[j], acc[j]);
    }
    *(float4*)(g + gi * 4) = make_float4(relu_(acc[0]), relu_(acc[1]), relu_(acc[2]), relu_(acc[3]));
}

// ---------------- readout ----------------
__global__ __launch_bounds__(256) void k_readout(
    const float* __restrict__ nbuf, const float* __restrict__ g,
    const float* __restrict__ Rn, const float* __restrict__ Rn_b,
    const float* __restrict__ Rg, const float* __restrict__ Rg_b,
    float* __restrict__ out)
{
    int i = blockIdx.x * 256 + threadIdx.x;
    if (i < NNODES) {
        const float* np = nbuf + (size_t)i * 16;
        float acc = Rn_b[0];
#pragma unroll
        for (int k = 0; k < 16; k++) acc = fmaf(np[k], Rn[k], acc);
        out[i] = sigmoid_(acc);
    } else if (i < NNODES + NG) {
        int gi = i - NNODES;
        const float* gp = g + gi * 4;
        float acc = Rg_b[0];
#pragma unroll
        for (int k = 0; k < 4; k++) acc = fmaf(gp[k], Rg[k], acc);
        out[i] = sigmoid_(acc);
    }
}

extern "C" void kernel_launch(void* const* d_in, const int* in_sizes, int n_in,
                              void* d_out, int out_size, void* d_ws, size_t ws_size,
                              hipStream_t stream) {
    const float* nodes      = (const float*)d_in[0];
    const float* edges      = (const float*)d_in[1];
    const int*   senders    = (const int*)d_in[2];
    const int*   receivers  = (const int*)d_in[3];
    const int*   node_graph = (const int*)d_in[4];
    const float* We1 = (const float*)d_in[5];
    const float* be1 = (const float*)d_in[6];
    const float* Wn1 = (const float*)d_in[7];
    const float* bn1 = (const float*)d_in[8];
    const float* We2 = (const float*)d_in[9];
    const float* be2 = (const float*)d_in[10];
    const float* Wn2 = (const float*)d_in[11];
    const float* bn2 = (const float*)d_in[12];
    const float* Wg2 = (const float*)d_in[13];
    const float* bg2 = (const float*)d_in[14];
    const float* He_e = (const float*)d_in[15];
    const float* He_s = (const float*)d_in[16];
    const float* He_g = (const float*)d_in[17];
    const float* He_b = (const float*)d_in[18];
    const float* Hn_n = (const float*)d_in[19];
    const float* Hn_in = (const float*)d_in[20];
    const float* Hn_g = (const float*)d_in[21];
    const float* Hn_b = (const float*)d_in[22];
    const float* Hg_e = (const float*)d_in[23];
    const float* Hg_n = (const float*)d_in[24];
    const float* Hg_g = (const float*)d_in[25];
    const float* Hg_b = (const float*)d_in[26];
    const float* Rn   = (const float*)d_in[27];
    const float* Rn_b = (const float*)d_in[28];
    const float* Rg   = (const float*)d_in[29];
    const float* Rg_b = (const float*)d_in[30];
    float* out = (float*)d_out;

    // ---- workspace layout ----
    char* p = (char*)d_ws;
    float* e         = (float*)p;                p += (size_t)NEDGES * 8 * 4;   // 102.4 MB
    int*   senders_s = (int*)p;                  p += (size_t)NEDGES * 4;       // 12.8 MB
    float* nbuf      = (float*)p;                p += (size_t)NNODES * 16 * 4;  // 12.8 MB
    float* slab      = (float*)p;                p += (size_t)NSLAB * NG * 8 * 4; // 4 MB
    int*   deg       = (int*)p;                  p += (size_t)NNODES * 4;       // zero region start
    float* ecount    = (float*)p;                p += (size_t)NG * 4;           // zero region end
    int*   off       = (int*)p;                  p += (size_t)(NNODES + 4) * 4;
    int*   cursor    = (int*)p;                  p += (size_t)NNODES * 4;
    int*   goff      = (int*)p;                  p += (size_t)(NG + 4) * 4;
    int*   bsum      = (int*)p;                  p += (size_t)NB1 * 4 + 8;
    int*   bpre      = (int*)p;                  p += (size_t)NB1 * 4 + 8;
    float* gsum_n    = (float*)p;                p += (size_t)NG * 16 * 4;
    float* gsum_e    = (float*)p;                p += (size_t)NG * 8 * 4;
    float* g         = (float*)p;                p += (size_t)NG * 4 * 4;

    // zero only deg + ecount (everything else is fully rewritten each launch)
    hipMemsetAsync(deg, 0, ((size_t)NNODES + NG) * 4, stream);

    // ---- build receiver-sorted CSR (once per launch) ----
    k_deg<<<1024, 256, 0, stream>>>(receivers, deg);
    k_scan1<<<NB1, 256, 0, stream>>>(deg, bsum);
    k_scan2<<<1, 64, 0, stream>>>(bsum, bpre);
    k_scan3<<<NB1, 256, 0, stream>>>(deg, bpre, off, cursor);
    k_goff<<<(NNODES + 255) / 256, 256, 0, stream>>>(node_graph, goff);

    // ---- encoders ----
    k_node_enc<<<(NNODES + 255) / 256, 256, 0, stream>>>(nodes, Wn1, bn1, Wn2, bn2, nbuf);
    k_edge_enc_scatter<<<2048, 256, 0, stream>>>(edges, senders, receivers, node_graph,
                                                 We1, be1, We2, be2, cursor, e, senders_s, ecount);
    k_gsum_nodes<<<NG, 256, 0, stream>>>(nbuf, goff, gsum_n);
    k_g_enc<<<1, NG, 0, stream>>>(gsum_n, goff, Wg2, bg2, g);

    // ---- hops ----
    for (int h = 0; h < 3; h++) {
        k_edge_hop<<<NSLAB, 256, 0, stream>>>(e, nbuf, g, senders_s, node_graph,
                                              He_e, He_s, He_g, He_b, slab);
        k_gred_e<<<NG * 8 / 256, 256, 0, stream>>>(slab, gsum_e);
        k_node_hop<<<(NNODES + 255) / 256, 256, 0, stream>>>(nbuf, e, off, g, node_graph,
                                                             Hn_n, Hn_in, Hn_g, Hn_b);
        k_gsum_nodes<<<NG, 256, 0, stream>>>(nbuf, goff, gsum_n);
        k_g_hop<<<1, NG, 0, stream>>>(g, gsum_e, gsum_n, ecount, goff,
                                      Hg_e, Hg_n, Hg_g, Hg_b);
    }
    k_readout<<<(NNODES + NG + 255) / 256, 256, 0, stream>>>(nbuf, g, Rn, Rn_b, Rg, Rg_b, out);
}